// Round 4
// baseline (285.067 us; speedup 1.0000x reference)
//
#include <hip/hip_runtime.h>
#include <math.h>

#define BB 16
#define QQ 900
#define CC 91
#define TT 100
#define BT (BB * TT)                    // 1600
#define NTHREADS 256
#define TILE 15                         // query rows per cost block
#define NBLK_PER_IMG (QQ / TILE)        // 60
#define COST_BLOCKS (BB * NBLK_PER_IMG) // 960
#define NSLOT 15                        // ceil(900/64) row slots per lane
#define WSCOLS 128                      // u64 workspace slots per image
#define PENDK 8                         // pending-buffer slots
#define RB 5                            // row register-block (15 = 3 passes)
#define DONE_TGT 0xFFFFFFC3u            // 0xFFFFFFFF - 60 (countdown target)

__device__ __forceinline__ unsigned ordkey(float f) {
    unsigned u = __float_as_uint(f);
    return (u & 0x80000000u) ? ~u : (u | 0x80000000u);
}
__device__ __forceinline__ unsigned long long u64min(unsigned long long a, unsigned long long b) {
    return a < b ? a : b;
}
__device__ __forceinline__ unsigned long long u64max(unsigned long long a, unsigned long long b) {
    return a > b ? a : b;
}
// pack (key,row,col) -> u64; lexicographic == numpy flat-index argmin order
__device__ __forceinline__ unsigned long long packkrc(unsigned key, int row, int col) {
    return ((unsigned long long)key << 21) | ((unsigned long long)row << 11) | (unsigned)col;
}
__device__ __forceinline__ unsigned long long rdlane64(unsigned long long v, int l) {
    unsigned lo = (unsigned)__builtin_amdgcn_readlane((int)(unsigned)v, l);
    unsigned hi = (unsigned)__builtin_amdgcn_readlane((int)(unsigned)(v >> 32), l);
    return ((unsigned long long)hi << 32) | lo;
}

// cooperative rescan of column cc over alive rows; L2-bypassing loads (cross-XCD fresh)
__device__ __forceinline__ unsigned long long rescan_col(
    const float* __restrict__ cb, const unsigned char* s_dead, int cc, int lane)
{
    unsigned long long best = ~0ULL;
    #pragma unroll
    for (int i = 0; i < NSLOT; ++i) {
        int r = i * 64 + lane;
        if (r < QQ && s_dead[r] == 0) {
            float v = __hip_atomic_load(cb + (size_t)r * BT + cc,
                                        __ATOMIC_RELAXED, __HIP_MEMORY_SCOPE_AGENT);
            best = u64min(best, packkrc(ordkey(v), r, cc));
        }
    }
    #pragma unroll
    for (int off = 1; off < 64; off <<= 1)
        best = u64min(best, __shfl_xor(best, off, 64));
    return best;
}

struct SmCost {
    float4 t[BT];           // 25.6 KB AoS targets
    int    lab[BT];         // 6.4 KB
    float  sig[TILE][CC];   // 5.46 KB
    float  row[TILE][8];    // px,py,pz,pw,x0,y0,x1,y1
};
struct SmGreedy {
    unsigned fr[1024];      // first-rank-per-row table (one-time)
    unsigned dead32[256];   // 1024 B row-dead flags (monotonic)
};
union SmAll { SmCost c; SmGreedy g; };

// ---------------------------------------------------------------------------
// Fused kernel. Blocks [0,960): cost tiles (bit-exact math, 5-row register
// blocking). Blocks [960,976): per-image greedy matcher, released by a
// per-image done-countdown -> greedy(image b) overlaps cost(images > b).
// Deadlock-free: cost blocks never wait; greedy blocks only wait on them.
// ---------------------------------------------------------------------------
__global__ __launch_bounds__(NTHREADS, 4) void fused_kernel(
    const float* __restrict__ logits,
    const float* __restrict__ pred,
    const int*   __restrict__ tlab,
    const float* __restrict__ tbox,
    float*       __restrict__ cost,
    unsigned long long* __restrict__ colmin,
    unsigned*    __restrict__ done,
    float*       __restrict__ rows_out,
    float*       __restrict__ cols_out)
{
    __shared__ SmAll sm;

    if (blockIdx.x < COST_BLOCKS) {
        // =================== COST ROLE ===================
        const int b  = blockIdx.x / NBLK_PER_IMG;
        const int tb = blockIdx.x % NBLK_PER_IMG;
        const int r0 = tb * TILE;

        for (int j = threadIdx.x; j < BT; j += NTHREADS) {
            sm.c.t[j]   = *(const float4*)(tbox + (size_t)j * 4);
            sm.c.lab[j] = tlab[j];
        }
        for (int u = threadIdx.x; u < TILE * CC; u += NTHREADS) {
            int r = u / CC, c = u % CC;
            float x = logits[((size_t)(b * QQ + r0 + r)) * CC + c];
            sm.c.sig[r][c] = 1.0f / (1.0f + expf(-x));
        }
        if (threadIdx.x < TILE) {
            int r = threadIdx.x;
            const float4 p = *(const float4*)(pred + ((size_t)(b * QQ + r0 + r)) * 4);
            sm.c.row[r][0] = p.x; sm.c.row[r][1] = p.y;
            sm.c.row[r][2] = p.z; sm.c.row[r][3] = p.w;
            sm.c.row[r][4] = p.x - 0.5f * p.z;
            sm.c.row[r][5] = p.y - 0.5f * p.w;
            sm.c.row[r][6] = p.x + 0.5f * p.z;
            sm.c.row[r][7] = p.y + 0.5f * p.w;
        }
        __syncthreads();

        unsigned long long bestc = ~0ULL;   // column-min for col==threadIdx.x (<100)

        for (int p0 = 0; p0 < TILE; p0 += RB) {
            float qx[RB], qy[RB], qz[RB], qw[RB];
            float qx0[RB], qy0[RB], qx1[RB], qy1[RB], qa1[RB];
            #pragma unroll
            for (int rr = 0; rr < RB; ++rr) {
                const int r = p0 + rr;
                qx[rr]  = sm.c.row[r][0]; qy[rr]  = sm.c.row[r][1];
                qz[rr]  = sm.c.row[r][2]; qw[rr]  = sm.c.row[r][3];
                qx0[rr] = sm.c.row[r][4]; qy0[rr] = sm.c.row[r][5];
                qx1[rr] = sm.c.row[r][6]; qy1[rr] = sm.c.row[r][7];
                qa1[rr] = (qx1[rr] - qx0[rr]) * (qy1[rr] - qy0[rr]);
            }
            for (int j = threadIdx.x; j < BT; j += NTHREADS) {
                float4 t = sm.c.t[j];
                int id = sm.c.lab[j];
                float t_x0 = t.x - 0.5f * t.z, t_y0 = t.y - 0.5f * t.w;
                float t_x1 = t.x + 0.5f * t.z, t_y1 = t.y + 0.5f * t.w;
                float area2 = (t_x1 - t_x0) * (t_y1 - t_y0);
                #pragma unroll
                for (int rr = 0; rr < RB; ++rr) {
                    float cclass = -sm.c.sig[p0 + rr][id];
                    float cbbox = ((fabsf(qx[rr] - t.x) + fabsf(qy[rr] - t.y))
                                 + fabsf(qz[rr] - t.z)) + fabsf(qw[rr] - t.w);

                    float ltx = fmaxf(qx0[rr], t_x0), lty = fmaxf(qy0[rr], t_y0);
                    float rbx = fminf(qx1[rr], t_x1), rby = fminf(qy1[rr], t_y1);
                    float iw = fmaxf(rbx - ltx, 0.0f), ih = fmaxf(rby - lty, 0.0f);
                    float inter = iw * ih;
                    float uni = (qa1[rr] + area2) - inter;
                    float iou = inter / uni;

                    float ex0 = fminf(qx0[rr], t_x0), ey0 = fminf(qy0[rr], t_y0);
                    float ex1 = fmaxf(qx1[rr], t_x1), ey1 = fmaxf(qy1[rr], t_y1);
                    float ew = fmaxf(ex1 - ex0, 0.0f), eh = fmaxf(ey1 - ey0, 0.0f);
                    float ae = ew * eh;
                    float giou = iou - (ae - uni) / ae;

                    float v = (cbbox + cclass) + (-giou);
                    cost[((size_t)(b * QQ + r0 + p0 + rr)) * BT + j] = v;
                    if (j < TT)
                        bestc = u64min(bestc, packkrc(ordkey(v), r0 + p0 + rr, j));
                }
            }
        }

        if (threadIdx.x < TT)
            atomicMin(colmin + (size_t)b * WSCOLS + threadIdx.x, bestc);
        __threadfence();                 // flush cost stores device-wide
        __syncthreads();
        if (threadIdx.x == 0)
            atomicSub(done + b, 1u);     // device-scope release signal
        return;
    }

    // =================== GREEDY ROLE ===================
    const int b = blockIdx.x - COST_BLOCKS;
    if (threadIdx.x >= 64) return;       // single wave; no __syncthreads below
    const int lane = threadIdx.x;
    const float* cb = cost + (size_t)b * QQ * BT;
    unsigned char* s_dead = (unsigned char*)sm.g.dead32;

    #pragma unroll
    for (int k = 0; k < 16; ++k) sm.g.fr[lane + 64 * k] = 0xFFFFFFFFu;
    #pragma unroll
    for (int k = 0; k < 4; ++k) sm.g.dead32[lane + 64 * k] = 0u;

    // wait for this image's 60 cost tiles (acquire)
    while (__hip_atomic_load(done + b, __ATOMIC_ACQUIRE, __HIP_MEMORY_SCOPE_AGENT) != DONE_TGT)
        __builtin_amdgcn_s_sleep(2);
    __threadfence();

    // ---- load 100 column minima (L2-bypassing; written via device atomics) ----
    unsigned long long va = __hip_atomic_load(colmin + (size_t)b * WSCOLS + lane,
                                              __ATOMIC_RELAXED, __HIP_MEMORY_SCOPE_AGENT);
    unsigned long long vb = (lane < TT - 64)
        ? __hip_atomic_load(colmin + (size_t)b * WSCOLS + 64 + lane,
                            __ATOMIC_RELAXED, __HIP_MEMORY_SCOPE_AGENT)
        : ~0ULL;

    // ---- bitonic sort, 128 elements across 64 lanes x 2 regs, ascending ----
    #pragma unroll
    for (int k = 2; k <= 128; k <<= 1) {
        #pragma unroll
        for (int j = k >> 1; j > 0; j >>= 1) {
            if (j == 64) {
                unsigned long long lo = u64min(va, vb);
                unsigned long long hi = va ^ vb ^ lo;
                va = lo; vb = hi;
            } else {
                unsigned long long pa = __shfl_xor(va, j, 64);
                bool ta = ((lane & j) == 0) == ((lane & k) == 0);
                va = ta ? u64min(va, pa) : u64max(va, pa);
                unsigned long long pb = __shfl_xor(vb, j, 64);
                int ib = lane + 64;
                bool tb_ = ((ib & j) == 0) == ((ib & k) == 0);
                vb = tb_ ? u64min(vb, pb) : u64max(vb, pb);
            }
        }
    }

    const int rA = (int)((va >> 11) & 0x3FF);
    const int cA = (int)(va & 0x7FF);
    const int rB = (int)((vb >> 11) & 0x3FF);
    const int cB = (int)(vb & 0x7FF);

    // ---- one-time firstdup table: fd = smallest earlier rank with same row ----
    atomicMin(&sm.g.fr[rA], (unsigned)lane);
    atomicMin(&sm.g.fr[rB], (unsigned)(64 + lane));
    __threadfence_block();
    unsigned frA = sm.g.fr[rA], frB = sm.g.fr[rB];
    const unsigned fdA = (frA < (unsigned)lane)       ? frA : 0xFFFFFFFFu;
    const unsigned fdB = (frB < (unsigned)(64 + lane)) ? frB : 0xFFFFFFFFu;

    // ---- round loop: light bulk-pops + rare events ----
    unsigned long long pend[PENDK];
    #pragma unroll
    for (int t = 0; t < PENDK; ++t) pend[t] = ~0ULL;
    unsigned long long pmin = ~0ULL;

    int cur = 0, m = 0, guard = 0;
    while (m < TT && ++guard < 4096) {
        __threadfence_block();           // order prior ds_writes before reads
        bool dA = s_dead[rA] != 0;
        bool dB = s_dead[rB] != 0;

        bool evA = (lane >= cur) &&
                   (dA || (fdA != 0xFFFFFFFFu && fdA >= (unsigned)cur) || (pmin < va));
        bool evB = ((64 + lane) >= cur) &&
                   (dB || (fdB != 0xFFFFFFFFu && fdB >= (unsigned)cur) || (pmin < vb));
        unsigned long long mA = __ballot(evA);
        unsigned long long mB = __ballot(evB);
        int k = mA ? (int)__ffsll(mA) - 1
              : (mB ? 64 + (int)__ffsll(mB) - 1 : 128);

        int n = k - cur;
        if (n > TT - m) n = TT - m;
        if (n > 0) {
            // bulk match ranks [cur, cur+n): alive, unique rows
            int iA = lane - cur;
            if (iA >= 0 && iA < n) {
                rows_out[b * TT + m + iA] = (float)rA;
                cols_out[b * TT + m + iA] = (float)cA;
                s_dead[rA] = 1;
            }
            int iB = 64 + lane - cur;
            if (iB >= 0 && iB < n) {
                rows_out[b * TT + m + iB] = (float)rB;
                cols_out[b * TT + m + iB] = (float)cB;
                s_dead[rB] = 1;
            }
            m += n; cur += n;
            if (m >= TT) break;
        }

        // ---- single event at rank cur ----
        unsigned long long ecur = (cur < 64) ? rdlane64(va, cur)
                                : (cur < 128) ? rdlane64(vb, cur - 64) : ~0ULL;
        __threadfence_block();           // bulk deaths visible before reads

        if (pmin < ecur) {
            // pop pending entry
            unsigned long long e = pmin;
            bool removed = false;
            #pragma unroll
            for (int t = 0; t < PENDK; ++t)
                if (!removed && pend[t] == e) { pend[t] = ~0ULL; removed = true; }
            pmin = ~0ULL;
            #pragma unroll
            for (int t = 0; t < PENDK; ++t) pmin = u64min(pmin, pend[t]);

            int re = (int)((e >> 11) & 0x3FF);
            int ce = (int)(e & 0x7FF);
            bool alive = (s_dead[re] == 0);    // same-addr broadcast read
            if (alive) {
                if (lane == 0) {
                    rows_out[b * TT + m] = (float)re;
                    cols_out[b * TT + m] = (float)ce;
                    s_dead[re] = 1;
                }
                ++m;
            } else {
                unsigned long long best = rescan_col(cb, s_dead, ce, lane);
                bool placed = false;
                #pragma unroll
                for (int t = 0; t < PENDK; ++t)
                    if (!placed && pend[t] == ~0ULL) { pend[t] = best; placed = true; }
                pmin = u64min(pmin, best);
            }
        } else if (cur < 128) {
            // sorted entry at cur is stale (row dead): rescan its column
            int ccur = (int)(ecur & 0x7FF);
            unsigned long long best = rescan_col(cb, s_dead, ccur, lane);
            bool placed = false;
            #pragma unroll
            for (int t = 0; t < PENDK; ++t)
                if (!placed && pend[t] == ~0ULL) { pend[t] = best; placed = true; }
            pmin = u64min(pmin, best);
            ++cur;
        }
    }
}

extern "C" void kernel_launch(void* const* d_in, const int* in_sizes, int n_in,
                              void* d_out, int out_size, void* d_ws, size_t ws_size,
                              hipStream_t stream) {
    const float* logits = (const float*)d_in[0];   // [16,900,91]
    const float* pred   = (const float*)d_in[1];   // [16,900,4]
    const int*   tlab   = (const int*)d_in[2];     // [16,100]
    const float* tbox   = (const float*)d_in[3];   // [16,100,4]

    float* out = (float*)d_out;
    float* cost = out;                              // 23,040,000
    float* rows = out + (size_t)BB * QQ * BT;       // 1600
    float* cols = rows + (size_t)BB * TT;           // 1600

    unsigned long long* colmin = (unsigned long long*)d_ws;          // 16*128*8 = 16384 B
    unsigned* done = (unsigned*)((char*)d_ws + (size_t)BB * WSCOLS * 8);  // 16*4 = 64 B

    // 0xFF-fill: colmin sentinels (~0ULL) AND done countdown start (0xFFFFFFFF)
    hipMemsetAsync(d_ws, 0xFF, (size_t)BB * WSCOLS * 8 + (size_t)BB * 4, stream);

    fused_kernel<<<COST_BLOCKS + BB, NTHREADS, 0, stream>>>(
        logits, pred, tlab, tbox, cost, colmin, done, rows, cols);
}

// Round 7
// 203.958 us; speedup vs baseline: 1.3977x; 1.3977x over previous
//
#include <hip/hip_runtime.h>
#include <math.h>

#define BB 16
#define QQ 900
#define CC 91
#define TT 100
#define BT (BB * TT)                    // 1600
#define NTHREADS 256
#define TILE 15                         // query rows per cost block
#define NBLK_PER_IMG (QQ / TILE)        // 60
#define COST_BLOCKS (BB * NBLK_PER_IMG) // 960
#define NSLOT 15                        // ceil(900/64) row slots per lane
#define PENDK 8                         // pending-buffer slots
#define RB 5                            // row register-block (15 = 3 passes)
// per-tile column-minima slots: slots[b][tile][c], c<100. Written
// unconditionally every iteration -> NO initialization / memset needed.
#define SLOT_STRIDE 100

__device__ __forceinline__ unsigned ordkey(float f) {
    unsigned u = __float_as_uint(f);
    return (u & 0x80000000u) ? ~u : (u | 0x80000000u);
}
__device__ __forceinline__ unsigned long long u64min(unsigned long long a, unsigned long long b) {
    return a < b ? a : b;
}
__device__ __forceinline__ unsigned long long u64max(unsigned long long a, unsigned long long b) {
    return a > b ? a : b;
}
// pack (key,row,col) -> u64; lexicographic == numpy flat-index argmin order
__device__ __forceinline__ unsigned long long packkrc(unsigned key, int row, int col) {
    return ((unsigned long long)key << 21) | ((unsigned long long)row << 11) | (unsigned)col;
}
__device__ __forceinline__ unsigned long long rdlane64(unsigned long long v, int l) {
    unsigned lo = (unsigned)__builtin_amdgcn_readlane((int)(unsigned)v, l);
    unsigned hi = (unsigned)__builtin_amdgcn_readlane((int)(unsigned)(v >> 32), l);
    return ((unsigned long long)hi << 32) | lo;
}

// ---------------------------------------------------------------------------
// Kernel 1: cost[b,q,j], tiled 15 rows/block (R4-verified math, bit-exact).
// Each tile writes its local column minima (cols 0..99) to its own slot row
// -- plain stores, no atomics, no sentinel init.
// ---------------------------------------------------------------------------
__global__ __launch_bounds__(NTHREADS) void cost_kernel(
    const float* __restrict__ logits,
    const float* __restrict__ pred,
    const int*   __restrict__ tlab,
    const float* __restrict__ tbox,
    float*       __restrict__ cost,
    unsigned long long* __restrict__ slots)
{
    const int b  = blockIdx.x / NBLK_PER_IMG;
    const int tb = blockIdx.x % NBLK_PER_IMG;
    const int r0 = tb * TILE;

    __shared__ float4 s_t[BT];                // 25.6 KB AoS targets
    __shared__ int    s_lab[BT];
    __shared__ float  s_sig[TILE][CC];
    __shared__ float  s_row[TILE][8];         // px,py,pz,pw,x0,y0,x1,y1

    for (int j = threadIdx.x; j < BT; j += NTHREADS) {
        s_t[j]   = *(const float4*)(tbox + (size_t)j * 4);
        s_lab[j] = tlab[j];
    }
    for (int u = threadIdx.x; u < TILE * CC; u += NTHREADS) {
        int r = u / CC, c = u % CC;
        float x = logits[((size_t)(b * QQ + r0 + r)) * CC + c];
        s_sig[r][c] = 1.0f / (1.0f + expf(-x));
    }
    if (threadIdx.x < TILE) {
        int r = threadIdx.x;
        const float4 p = *(const float4*)(pred + ((size_t)(b * QQ + r0 + r)) * 4);
        s_row[r][0] = p.x; s_row[r][1] = p.y;
        s_row[r][2] = p.z; s_row[r][3] = p.w;
        s_row[r][4] = p.x - 0.5f * p.z;
        s_row[r][5] = p.y - 0.5f * p.w;
        s_row[r][6] = p.x + 0.5f * p.z;
        s_row[r][7] = p.y + 0.5f * p.w;
    }
    __syncthreads();

    unsigned long long bestc = ~0ULL;   // column-min for col==threadIdx.x (<100)

    for (int p0 = 0; p0 < TILE; p0 += RB) {
        float qx[RB], qy[RB], qz[RB], qw[RB];
        float qx0[RB], qy0[RB], qx1[RB], qy1[RB], qa1[RB];
        #pragma unroll
        for (int rr = 0; rr < RB; ++rr) {
            const int r = p0 + rr;
            qx[rr]  = s_row[r][0]; qy[rr]  = s_row[r][1];
            qz[rr]  = s_row[r][2]; qw[rr]  = s_row[r][3];
            qx0[rr] = s_row[r][4]; qy0[rr] = s_row[r][5];
            qx1[rr] = s_row[r][6]; qy1[rr] = s_row[r][7];
            qa1[rr] = (qx1[rr] - qx0[rr]) * (qy1[rr] - qy0[rr]);
        }
        for (int j = threadIdx.x; j < BT; j += NTHREADS) {
            float4 t = s_t[j];
            int id = s_lab[j];
            float t_x0 = t.x - 0.5f * t.z, t_y0 = t.y - 0.5f * t.w;
            float t_x1 = t.x + 0.5f * t.z, t_y1 = t.y + 0.5f * t.w;
            float area2 = (t_x1 - t_x0) * (t_y1 - t_y0);
            #pragma unroll
            for (int rr = 0; rr < RB; ++rr) {
                float cclass = -s_sig[p0 + rr][id];
                float cbbox = ((fabsf(qx[rr] - t.x) + fabsf(qy[rr] - t.y))
                             + fabsf(qz[rr] - t.z)) + fabsf(qw[rr] - t.w);

                float ltx = fmaxf(qx0[rr], t_x0), lty = fmaxf(qy0[rr], t_y0);
                float rbx = fminf(qx1[rr], t_x1), rby = fminf(qy1[rr], t_y1);
                float iw = fmaxf(rbx - ltx, 0.0f), ih = fmaxf(rby - lty, 0.0f);
                float inter = iw * ih;
                float uni = (qa1[rr] + area2) - inter;
                float iou = inter / uni;

                float ex0 = fminf(qx0[rr], t_x0), ey0 = fminf(qy0[rr], t_y0);
                float ex1 = fmaxf(qx1[rr], t_x1), ey1 = fmaxf(qy1[rr], t_y1);
                float ew = fmaxf(ex1 - ex0, 0.0f), eh = fmaxf(ey1 - ey0, 0.0f);
                float ae = ew * eh;
                float giou = iou - (ae - uni) / ae;

                float v = (cbbox + cclass) + (-giou);
                cost[((size_t)(b * QQ + r0 + p0 + rr)) * BT + j] = v;
                if (j < TT)
                    bestc = u64min(bestc, packkrc(ordkey(v), r0 + p0 + rr, j));
            }
        }
    }

    if (threadIdx.x < TT)
        slots[((size_t)(b * NBLK_PER_IMG) + tb) * SLOT_STRIDE + threadIdx.x] = bestc;
}

// ---------------------------------------------------------------------------
// Kernel 2: greedy matcher (separate dispatch: ordering + cross-XCD
// visibility guaranteed by the stream -- the R2/R3-verified model).
// Prologue reduces 60 per-tile slots per column, then the R4-verified
// sorted lazy-deletion walk with bulk pops.
// ---------------------------------------------------------------------------
__global__ __launch_bounds__(64, 1) void greedy_kernel(
    const float* __restrict__ cost,
    const unsigned long long* __restrict__ slots,
    float*       __restrict__ rows_out,
    float*       __restrict__ cols_out)
{
    const int b = blockIdx.x;
    const int lane = threadIdx.x;
    const float* cb = cost + (size_t)b * QQ * BT;

    __shared__ unsigned s_fr[1024];        // first-rank-per-row (one-time)
    __shared__ unsigned s_dead32[256];     // 1024 B row-dead flags (monotonic)
    unsigned char* s_dead = (unsigned char*)s_dead32;

    #pragma unroll
    for (int k = 0; k < 16; ++k) s_fr[lane + 64 * k] = 0xFFFFFFFFu;
    #pragma unroll
    for (int k = 0; k < 4; ++k) s_dead32[lane + 64 * k] = 0u;

    // ---- reduce 60 per-tile slots -> column minima (cols lane, lane+64) ----
    const unsigned long long* sb = slots + (size_t)b * NBLK_PER_IMG * SLOT_STRIDE;
    unsigned long long va = ~0ULL, vb = ~0ULL;
    #pragma unroll 10
    for (int t = 0; t < NBLK_PER_IMG; ++t) {
        va = u64min(va, sb[(size_t)t * SLOT_STRIDE + lane]);
        if (lane < TT - 64)
            vb = u64min(vb, sb[(size_t)t * SLOT_STRIDE + 64 + lane]);
    }

    // ---- bitonic sort, 128 elements across 64 lanes x 2 regs, ascending ----
    #pragma unroll
    for (int k = 2; k <= 128; k <<= 1) {
        #pragma unroll
        for (int j = k >> 1; j > 0; j >>= 1) {
            if (j == 64) {
                unsigned long long lo = u64min(va, vb);
                unsigned long long hi = va ^ vb ^ lo;
                va = lo; vb = hi;
            } else {
                unsigned long long pa = __shfl_xor(va, j, 64);
                bool ta = ((lane & j) == 0) == ((lane & k) == 0);
                va = ta ? u64min(va, pa) : u64max(va, pa);
                unsigned long long pb = __shfl_xor(vb, j, 64);
                int ib = lane + 64;
                bool tb_ = ((ib & j) == 0) == ((ib & k) == 0);
                vb = tb_ ? u64min(vb, pb) : u64max(vb, pb);
            }
        }
    }

    const int rA = (int)((va >> 11) & 0x3FF);
    const int cA = (int)(va & 0x7FF);
    const int rB = (int)((vb >> 11) & 0x3FF);
    const int cB = (int)(vb & 0x7FF);

    // ---- one-time firstdup: smallest earlier rank with same row ----
    atomicMin(&s_fr[rA], (unsigned)lane);
    atomicMin(&s_fr[rB], (unsigned)(64 + lane));
    __threadfence_block();
    unsigned frA = s_fr[rA], frB = s_fr[rB];
    const unsigned fdA = (frA < (unsigned)lane)        ? frA : 0xFFFFFFFFu;
    const unsigned fdB = (frB < (unsigned)(64 + lane)) ? frB : 0xFFFFFFFFu;

    // ---- round loop: light bulk-pops + rare events (R4-verified) ----
    unsigned long long pend[PENDK];
    #pragma unroll
    for (int t = 0; t < PENDK; ++t) pend[t] = ~0ULL;
    unsigned long long pmin = ~0ULL;

    int cur = 0, m = 0, guard = 0;
    while (m < TT && ++guard < 2048) {
        __threadfence_block();
        bool dA = s_dead[rA] != 0;
        bool dB = s_dead[rB] != 0;

        bool evA = (lane >= cur) &&
                   (dA || (fdA != 0xFFFFFFFFu && fdA >= (unsigned)cur) || (pmin < va));
        bool evB = ((64 + lane) >= cur) &&
                   (dB || (fdB != 0xFFFFFFFFu && fdB >= (unsigned)cur) || (pmin < vb));
        unsigned long long mA = __ballot(evA);
        unsigned long long mB = __ballot(evB);
        int k = mA ? (int)__ffsll(mA) - 1
              : (mB ? 64 + (int)__ffsll(mB) - 1 : 128);

        int n = k - cur;
        if (n > TT - m) n = TT - m;
        if (n > 0) {
            // bulk match ranks [cur, cur+n): alive, unique rows
            int iA = lane - cur;
            if (iA >= 0 && iA < n) {
                rows_out[b * TT + m + iA] = (float)rA;
                cols_out[b * TT + m + iA] = (float)cA;
                s_dead[rA] = 1;
            }
            int iB = 64 + lane - cur;
            if (iB >= 0 && iB < n) {
                rows_out[b * TT + m + iB] = (float)rB;
                cols_out[b * TT + m + iB] = (float)cB;
                s_dead[rB] = 1;
            }
            m += n; cur += n;
            if (m >= TT) break;
        }

        // ---- single event at rank cur ----
        unsigned long long ecur = (cur < 64) ? rdlane64(va, cur)
                                : (cur < 128) ? rdlane64(vb, cur - 64) : ~0ULL;
        __threadfence_block();

        if (pmin < ecur) {
            // pop pending entry
            unsigned long long e = pmin;
            bool removed = false;
            #pragma unroll
            for (int t = 0; t < PENDK; ++t)
                if (!removed && pend[t] == e) { pend[t] = ~0ULL; removed = true; }
            pmin = ~0ULL;
            #pragma unroll
            for (int t = 0; t < PENDK; ++t) pmin = u64min(pmin, pend[t]);

            int re = (int)((e >> 11) & 0x3FF);
            int ce = (int)(e & 0x7FF);
            bool alive = (s_dead[re] == 0);    // same-addr broadcast read
            if (alive) {
                if (lane == 0) {
                    rows_out[b * TT + m] = (float)re;
                    cols_out[b * TT + m] = (float)ce;
                    s_dead[re] = 1;
                }
                ++m;
            } else {
                // rescan column ce over alive rows (plain cached loads:
                // cross-kernel visibility is guaranteed at dispatch boundary)
                unsigned long long best = ~0ULL;
                #pragma unroll
                for (int i = 0; i < NSLOT; ++i) {
                    int r = i * 64 + lane;
                    if (r < QQ && s_dead[r] == 0) {
                        float v = cb[(size_t)r * BT + ce];
                        best = u64min(best, packkrc(ordkey(v), r, ce));
                    }
                }
                #pragma unroll
                for (int off = 1; off < 64; off <<= 1)
                    best = u64min(best, __shfl_xor(best, off, 64));
                bool placed = false;
                #pragma unroll
                for (int t = 0; t < PENDK; ++t)
                    if (!placed && pend[t] == ~0ULL) { pend[t] = best; placed = true; }
                pmin = u64min(pmin, best);
            }
        } else if (cur < 128) {
            // sorted entry at cur is stale (row dead): rescan its column
            int ccur = (int)(ecur & 0x7FF);
            unsigned long long best = ~0ULL;
            #pragma unroll
            for (int i = 0; i < NSLOT; ++i) {
                int r = i * 64 + lane;
                if (r < QQ && s_dead[r] == 0) {
                    float v = cb[(size_t)r * BT + ccur];
                    best = u64min(best, packkrc(ordkey(v), r, ccur));
                }
            }
            #pragma unroll
            for (int off = 1; off < 64; off <<= 1)
                best = u64min(best, __shfl_xor(best, off, 64));
            bool placed = false;
            #pragma unroll
            for (int t = 0; t < PENDK; ++t)
                if (!placed && pend[t] == ~0ULL) { pend[t] = best; placed = true; }
            pmin = u64min(pmin, best);
            ++cur;
        }
    }
}

extern "C" void kernel_launch(void* const* d_in, const int* in_sizes, int n_in,
                              void* d_out, int out_size, void* d_ws, size_t ws_size,
                              hipStream_t stream) {
    const float* logits = (const float*)d_in[0];   // [16,900,91]
    const float* pred   = (const float*)d_in[1];   // [16,900,4]
    const int*   tlab   = (const int*)d_in[2];     // [16,100]
    const float* tbox   = (const float*)d_in[3];   // [16,100,4]

    float* out = (float*)d_out;
    float* cost = out;                              // 23,040,000
    float* rows = out + (size_t)BB * QQ * BT;       // 1600
    float* cols = rows + (size_t)BB * TT;           // 1600

    // per-tile slots: 16*60*100*8 = 768,000 B; written unconditionally
    // every launch -> no initialization dispatch required.
    unsigned long long* slots = (unsigned long long*)d_ws;

    cost_kernel<<<COST_BLOCKS, NTHREADS, 0, stream>>>(logits, pred, tlab, tbox, cost, slots);
    greedy_kernel<<<BB, 64, 0, stream>>>(cost, slots, rows, cols);
}